// Round 5
// baseline (3586.513 us; speedup 1.0000x reference)
//
#include <hip/hip_runtime.h>
#include <math.h>

#define B_DIM 4
#define T_DIM 2048
#define D_DIM 1024
#define ETA 0.1f
#define N_ITERS 10

typedef unsigned short u16;
typedef __attribute__((ext_vector_type(8))) short bf8_t;   // 8 bf16 (4 VGPRs)
typedef __attribute__((ext_vector_type(4))) float f4_t;    // 4 fp32 acc

__device__ __forceinline__ u16 f2bf(float f) {
  union { float f; unsigned u; } x;
  x.f = f;
  unsigned r = x.u + 0x7FFFu + ((x.u >> 16) & 1u);  // RNE
  return (u16)(r >> 16);
}
__device__ __forceinline__ float bf_lo(unsigned pk) {
  union { unsigned u; float f; } x; x.u = pk << 16; return x.f;
}
__device__ __forceinline__ float bf_hi(unsigned pk) {
  union { unsigned u; float f; } x; x.u = pk & 0xFFFF0000u; return x.f;
}

__device__ __forceinline__ float soft_thresh(float v, float lam) {
  return copysignf(fmaxf(fabsf(v) - lam, 0.0f), v);
}

// ---------------------------------------------------------------------------
// bf16 MFMA NT GEMM core: C(128x128 at m0,n0) = A[M x K] * B^T (B is [N][K]).
// 256 threads = 4 waves (2x2), each wave 64x64 = 4x4 mfma 16x16x32 tiles.
// ---------------------------------------------------------------------------
__device__ __forceinline__ void mfma_gemm_nt(const u16* __restrict__ A,
                                             const u16* __restrict__ Bm,
                                             int lda, int ldb,
                                             int m0, int n0, int kEnd,
                                             f4_t acc[4][4]) {
  __shared__ short As[128][72];
  __shared__ short Bs[128][72];
  const int tid = threadIdx.x;
  const int lane = tid & 63;
  const int wave = tid >> 6;
  const int m16 = lane & 15;
  const int q = lane >> 4;
  const int wrow = (wave >> 1) * 64;
  const int wcol = (wave & 1) * 64;
  const int sr = tid >> 3;   // staging row base (0..31)
  const int sc8 = tid & 7;   // k-octet (8 bf16 = 16B)

  float4 apf[4], bpf[4];
#pragma unroll
  for (int p = 0; p < 4; ++p) {
    apf[p] = *(const float4*)(A + (size_t)(m0 + sr + p * 32) * lda + sc8 * 8);
    bpf[p] = *(const float4*)(Bm + (size_t)(n0 + sr + p * 32) * ldb + sc8 * 8);
  }

  for (int k0 = 0; k0 < kEnd; k0 += 64) {
    __syncthreads();
#pragma unroll
    for (int p = 0; p < 4; ++p) {
      *(float4*)&As[sr + p * 32][sc8 * 8] = apf[p];
      *(float4*)&Bs[sr + p * 32][sc8 * 8] = bpf[p];
    }
    __syncthreads();
    if (k0 + 64 < kEnd) {
      const int kn = k0 + 64 + sc8 * 8;
#pragma unroll
      for (int p = 0; p < 4; ++p) {
        apf[p] = *(const float4*)(A + (size_t)(m0 + sr + p * 32) * lda + kn);
        bpf[p] = *(const float4*)(Bm + (size_t)(n0 + sr + p * 32) * ldb + kn);
      }
    }
#pragma unroll
    for (int s = 0; s < 2; ++s) {
      bf8_t af[4], bb[4];
#pragma unroll
      for (int i = 0; i < 4; ++i)
        af[i] = *(const bf8_t*)&As[wrow + i * 16 + m16][s * 32 + q * 8];
#pragma unroll
      for (int j = 0; j < 4; ++j)
        bb[j] = *(const bf8_t*)&Bs[wcol + j * 16 + m16][s * 32 + q * 8];
#pragma unroll
      for (int i = 0; i < 4; ++i)
#pragma unroll
        for (int j = 0; j < 4; ++j)
          acc[i][j] = __builtin_amdgcn_mfma_f32_16x16x32_bf16(
              af[i], bb[j], acc[i][j], 0, 0, 0);
    }
    __syncthreads();
  }
}

// C/D layout (verified m89): col = lane&15, row = (lane>>4)*4 + reg.
#define EPI_PREAMBLE                                   \
  const int tid = threadIdx.x;                         \
  const int lane = tid & 63;                           \
  const int wave = tid >> 6;                           \
  const int m16 = lane & 15;                           \
  const int q = lane >> 4;                             \
  const int wrow = (wave >> 1) * 64;                   \
  const int wcol = (wave & 1) * 64;

// ---------------------------------------------------------------------------
__global__ __launch_bounds__(256) void cvt_bf16_kernel(
    const float* __restrict__ src, u16* __restrict__ dst, int n4) {
  const int i = blockIdx.x * 256 + threadIdx.x;
  if (i >= n4) return;
  const float4 v = ((const float4*)src)[i];
  ushort4 o;
  o.x = f2bf(v.x); o.y = f2bf(v.y); o.z = f2bf(v.z); o.w = f2bf(v.w);
  ((ushort4*)dst)[i] = o;
}

// ---------------------------------------------------------------------------
__global__ __launch_bounds__(256) void prep_G_bf16_kernel(
    const float* __restrict__ Graw, u16* __restrict__ G) {
  const int idx = blockIdx.x * 256 + threadIdx.x;
  const int i = idx >> 10;
  const int j = idx & 1023;
  const float g =
      (i == j) ? 0.0f : 0.5f * (Graw[idx] + Graw[(size_t)j * D_DIM + i]);
  G[idx] = f2bf(g);
}

// ---------------------------------------------------------------------------
// qkv = x @ Wqkv^T. 1-D grid of 1536 blocks, supertile-swizzled.
// ---------------------------------------------------------------------------
__global__ __launch_bounds__(256) void qkv_mfma_kernel(
    const u16* __restrict__ xbf, const u16* __restrict__ Wbf,
    float* __restrict__ uq, float* __restrict__ uk, u16* __restrict__ vbf) {
  const int bid = blockIdx.x;
  const int g = bid / 192;
  const int r = bid % 192;
  const int m0 = (g * 8 + (r & 7)) * 128;
  const int n0 = (r >> 3) * 128;
  f4_t acc[4][4];
#pragma unroll
  for (int i = 0; i < 4; ++i)
#pragma unroll
    for (int j = 0; j < 4; ++j) acc[i][j] = (f4_t){0.f, 0.f, 0.f, 0.f};
  mfma_gemm_nt(xbf, Wbf, D_DIM, D_DIM, m0, n0, D_DIM, acc);
  EPI_PREAMBLE
  const int which = n0 >> 10;
  const int nloc0 = n0 & 1023;
#pragma unroll
  for (int i = 0; i < 4; ++i)
#pragma unroll
    for (int j = 0; j < 4; ++j) {
      const int cc = nloc0 + wcol + j * 16 + m16;
#pragma unroll
      for (int r2 = 0; r2 < 4; ++r2) {
        const size_t rr = m0 + wrow + i * 16 + q * 4 + r2;
        const float val = acc[i][j][r2];
        if (which == 0)       uq[rr * D_DIM + cc] = val;
        else if (which == 1)  uk[rr * D_DIM + cc] = val;
        else                  vbf[rr * D_DIM + cc] = f2bf(val);
      }
    }
}

// ---------------------------------------------------------------------------
__global__ __launch_bounds__(256) void transpose_bf16_kernel(
    const u16* __restrict__ src, u16* __restrict__ dst) {
  __shared__ short Ls[64][72];
  const int b = blockIdx.z;
  const int d0 = blockIdx.x * 64;
  const int t0 = blockIdx.y * 64;
  const int tid = threadIdx.x;
#pragma unroll
  for (int rep = 0; rep < 2; ++rep) {
    const int u = rep * 256 + tid;
    const int r = u >> 3;
    const int c8 = u & 7;
    const float4 v = *(const float4*)(src + (size_t)b * T_DIM * D_DIM +
                                      (size_t)(t0 + r) * D_DIM + d0 + c8 * 8);
    *(float4*)&Ls[r][c8 * 8] = v;
  }
  __syncthreads();
#pragma unroll
  for (int rep = 0; rep < 2; ++rep) {
    const int u = rep * 256 + tid;
    const int d = u >> 3;
    const int t8 = u & 7;
    union { u16 s[8]; float4 v; } tmp;
#pragma unroll
    for (int l = 0; l < 8; ++l) tmp.s[l] = (u16)Ls[t8 * 8 + l][d];
    *(float4*)(dst + (size_t)b * D_DIM * T_DIM + (size_t)(d0 + d) * T_DIM +
               t0 + t8 * 8) = tmp.v;
  }
}

// ---------------------------------------------------------------------------
// Fused LCA chain v2: all 10 iterations in one kernel.
// 512 threads = 8 waves; block owns 32 rows; wave owns 128 cols.
// v fp32 in regs (64), u bf16-packed in regs (32), acc 64, G-prefetch dbuf 64
// -> total <= 256 regs => 2 waves/SIMD. a single-buffered in LDS (66 KB),
// two barriers per iteration. G fragments register-double-buffered so MFMA
// never waits on the load it just issued.
// ---------------------------------------------------------------------------
__global__ __launch_bounds__(512, 2) void lca_fused_kernel(
    const float* __restrict__ uqg, const float* __restrict__ ukg,
    const u16* __restrict__ Gq, const u16* __restrict__ Gk,
    const float* __restrict__ llq, const float* __restrict__ llk,
    u16* __restrict__ aq_out, u16* __restrict__ ak_out) {
  __shared__ u16 a_lds[32][1032];  // row stride 2064 B: 16B-aligned, 2-way max
  const int b = blockIdx.x;
  const int chain = (b >> 2) & 1;                 // b%8: 0-3 q, 4-7 k (XCD map)
  const int mb = ((b >> 3) << 2) | (b & 3);       // 0..255
  const int m0 = mb * 32;
  const float* __restrict__ u = chain ? ukg : uqg;
  const u16* __restrict__ G = chain ? Gk : Gq;
  u16* __restrict__ aout = chain ? ak_out : aq_out;
  const float lam = expf(chain ? llk[0] : llq[0]);

  const int tid = threadIdx.x;
  const int lane = tid & 63;
  const int wave = tid >> 6;      // 0..7
  const int m16 = lane & 15;
  const int q = lane >> 4;
  const int col0 = wave * 128;    // wave's n-slice

  float vreg[2][8][4];
  unsigned upk[2][8][2];          // u as packed bf16 pairs (r0|r1, r2|r3)

  // ---- init: load u, v = ETA*u, a0 = soft(v)
#pragma unroll
  for (int rt = 0; rt < 2; ++rt)
#pragma unroll
    for (int c8 = 0; c8 < 8; ++c8) {
      const int row = rt * 16 + q * 4;
      const int col = col0 + c8 * 16 + m16;
#pragma unroll
      for (int p = 0; p < 2; ++p) {
        const float u0 = u[(size_t)(m0 + row + 2 * p + 0) * D_DIM + col];
        const float u1 = u[(size_t)(m0 + row + 2 * p + 1) * D_DIM + col];
        upk[rt][c8][p] = (unsigned)f2bf(u0) | ((unsigned)f2bf(u1) << 16);
        const float v0 = ETA * u0;
        const float v1 = ETA * u1;
        vreg[rt][c8][2 * p + 0] = v0;
        vreg[rt][c8][2 * p + 1] = v1;
        a_lds[row + 2 * p + 0][col] = f2bf(soft_thresh(v0, lam));
        a_lds[row + 2 * p + 1][col] = f2bf(soft_thresh(v1, lam));
      }
    }

  const u16* gbase = G + (size_t)(col0 + m16) * D_DIM + q * 8;

  for (int it = 1; it < N_ITERS; ++it) {
    __syncthreads();  // a_lds for this iteration fully written
    f4_t acc[2][8];
#pragma unroll
    for (int rt = 0; rt < 2; ++rt)
#pragma unroll
      for (int ct = 0; ct < 8; ++ct) acc[rt][ct] = (f4_t){0.f, 0.f, 0.f, 0.f};

    bf8_t bb0[8], bb1[8];
#pragma unroll
    for (int ct = 0; ct < 8; ++ct)
      bb0[ct] = *(const bf8_t*)(gbase + (size_t)ct * 16 * D_DIM);

    // K-loop unrolled by 64 (2 mfma-K steps): static dbuf indices
    for (int k0 = 0; k0 < D_DIM; k0 += 64) {
      // prefetch k0+32 into bb1 (k0+32 < 1024 always for k0 <= 960)
#pragma unroll
      for (int ct = 0; ct < 8; ++ct)
        bb1[ct] = *(const bf8_t*)(gbase + (size_t)ct * 16 * D_DIM + k0 + 32);
      {
        const bf8_t af0 = *(const bf8_t*)&a_lds[m16][k0 + q * 8];
        const bf8_t af1 = *(const bf8_t*)&a_lds[16 + m16][k0 + q * 8];
#pragma unroll
        for (int ct = 0; ct < 8; ++ct) {
          acc[0][ct] = __builtin_amdgcn_mfma_f32_16x16x32_bf16(
              af0, bb0[ct], acc[0][ct], 0, 0, 0);
          acc[1][ct] = __builtin_amdgcn_mfma_f32_16x16x32_bf16(
              af1, bb0[ct], acc[1][ct], 0, 0, 0);
        }
      }
      if (k0 + 64 < D_DIM) {
#pragma unroll
        for (int ct = 0; ct < 8; ++ct)
          bb0[ct] =
              *(const bf8_t*)(gbase + (size_t)ct * 16 * D_DIM + k0 + 64);
      }
      {
        const bf8_t af0 = *(const bf8_t*)&a_lds[m16][k0 + 32 + q * 8];
        const bf8_t af1 = *(const bf8_t*)&a_lds[16 + m16][k0 + 32 + q * 8];
#pragma unroll
        for (int ct = 0; ct < 8; ++ct) {
          acc[0][ct] = __builtin_amdgcn_mfma_f32_16x16x32_bf16(
              af0, bb1[ct], acc[0][ct], 0, 0, 0);
          acc[1][ct] = __builtin_amdgcn_mfma_f32_16x16x32_bf16(
              af1, bb1[ct], acc[1][ct], 0, 0, 0);
        }
      }
    }
    __syncthreads();  // all waves done READING a_lds; safe to overwrite
    const bool last = (it == N_ITERS - 1);
#pragma unroll
    for (int rt = 0; rt < 2; ++rt)
#pragma unroll
      for (int c8 = 0; c8 < 8; ++c8) {
        const int row = rt * 16 + q * 4;
        const int col = col0 + c8 * 16 + m16;
#pragma unroll
        for (int r = 0; r < 4; ++r) {
          const unsigned pk = upk[rt][c8][r >> 1];
          const float uu = (r & 1) ? bf_hi(pk) : bf_lo(pk);
          float v = vreg[rt][c8][r];
          v += ETA * (uu - v - acc[rt][c8][r]);
          vreg[rt][c8][r] = v;
          const u16 av = f2bf(soft_thresh(v, lam));
          a_lds[row + r][col] = av;
          if (last) aout[(size_t)(m0 + row + r) * D_DIM + col] = av;
        }
      }
  }
}

// ---------------------------------------------------------------------------
__global__ __launch_bounds__(256) void scores_mfma_kernel(
    const u16* __restrict__ aq, const u16* __restrict__ ak,
    float* __restrict__ sc) {
  const int b = blockIdx.z;
  const int m0 = blockIdx.y * 128;
  const int n0 = blockIdx.x * 128;
  if (n0 > m0 + 127) return;  // uniform early exit, before any barrier
  f4_t acc[4][4];
#pragma unroll
  for (int i = 0; i < 4; ++i)
#pragma unroll
    for (int j = 0; j < 4; ++j) acc[i][j] = (f4_t){0.f, 0.f, 0.f, 0.f};
  mfma_gemm_nt(aq + (size_t)b * T_DIM * D_DIM,
               ak + (size_t)b * T_DIM * D_DIM, D_DIM, D_DIM, m0, n0, D_DIM,
               acc);
  EPI_PREAMBLE
  float* out = sc + (size_t)b * T_DIM * T_DIM;
  const float scale = 0.03125f;  // 1/sqrt(1024)
#pragma unroll
  for (int i = 0; i < 4; ++i)
#pragma unroll
    for (int j = 0; j < 4; ++j) {
      const int cc = n0 + wcol + j * 16 + m16;
#pragma unroll
      for (int r = 0; r < 4; ++r) {
        const size_t rr = m0 + wrow + i * 16 + q * 4 + r;
        out[rr * T_DIM + cc] = acc[i][j][r] * scale;
      }
    }
}

// ---------------------------------------------------------------------------
__global__ __launch_bounds__(256) void softmax_attn_kernel(
    const float* __restrict__ sc, u16* __restrict__ attn) {
  const int b = blockIdx.x >> 11;
  const int i = blockIdx.x & (T_DIM - 1);
  const float* row = sc + ((size_t)b * T_DIM + i) * T_DIM;
  u16* arow = attn + ((size_t)b * T_DIM + i) * T_DIM;
  const int len = i + 1;
  const int tid = threadIdx.x;
  __shared__ float red[256];

  float mx = -INFINITY;
  for (int j = tid; j < len; j += 256) mx = fmaxf(mx, row[j]);
  red[tid] = mx;
  __syncthreads();
  for (int s = 128; s > 0; s >>= 1) {
    if (tid < s) red[tid] = fmaxf(red[tid], red[tid + s]);
    __syncthreads();
  }
  mx = red[0];
  __syncthreads();

  float sum = 0.0f;
  for (int j = tid; j < len; j += 256) sum += __expf(row[j] - mx);
  red[tid] = sum;
  __syncthreads();
  for (int s = 128; s > 0; s >>= 1) {
    if (tid < s) red[tid] += red[tid + s];
    __syncthreads();
  }
  const float inv = 1.0f / red[0];

  for (int j = tid; j < len; j += 256)
    arow[j] = f2bf(__expf(row[j] - mx) * inv);
  for (int j = len + tid; j < T_DIM; j += 256) arow[j] = 0;
}

// ---------------------------------------------------------------------------
__global__ __launch_bounds__(256) void attnv_mfma_kernel(
    const u16* __restrict__ attn, const u16* __restrict__ vT,
    u16* __restrict__ o1) {
  const int b = blockIdx.z;
  const int m0 = blockIdx.y * 128;
  const int n0 = blockIdx.x * 128;
  f4_t acc[4][4];
#pragma unroll
  for (int i = 0; i < 4; ++i)
#pragma unroll
    for (int j = 0; j < 4; ++j) acc[i][j] = (f4_t){0.f, 0.f, 0.f, 0.f};
  mfma_gemm_nt(attn + (size_t)b * T_DIM * T_DIM,
               vT + (size_t)b * D_DIM * T_DIM, T_DIM, T_DIM, m0, n0,
               m0 + 128, acc);
  EPI_PREAMBLE
  u16* out = o1 + (size_t)b * T_DIM * D_DIM;
#pragma unroll
  for (int i = 0; i < 4; ++i)
#pragma unroll
    for (int j = 0; j < 4; ++j) {
      const int cc = n0 + wcol + j * 16 + m16;
#pragma unroll
      for (int r = 0; r < 4; ++r) {
        const size_t rr = m0 + wrow + i * 16 + q * 4 + r;
        out[rr * D_DIM + cc] = f2bf(acc[i][j][r]);
      }
    }
}

// ---------------------------------------------------------------------------
__global__ __launch_bounds__(256) void out_mfma_kernel(
    const u16* __restrict__ o1, const u16* __restrict__ Wbf,
    float* __restrict__ out) {
  f4_t acc[4][4];
#pragma unroll
  for (int i = 0; i < 4; ++i)
#pragma unroll
    for (int j = 0; j < 4; ++j) acc[i][j] = (f4_t){0.f, 0.f, 0.f, 0.f};
  const int m0 = blockIdx.y * 128;
  const int n0 = blockIdx.x * 128;
  mfma_gemm_nt(o1, Wbf, D_DIM, D_DIM, m0, n0, D_DIM, acc);
  EPI_PREAMBLE
#pragma unroll
  for (int i = 0; i < 4; ++i)
#pragma unroll
    for (int j = 0; j < 4; ++j) {
      const int cc = n0 + wcol + j * 16 + m16;
#pragma unroll
      for (int r = 0; r < 4; ++r) {
        const size_t rr = m0 + wrow + i * 16 + q * 4 + r;
        out[rr * D_DIM + cc] = acc[i][j][r];
      }
    }
}

// ---------------------------------------------------------------------------
// Workspace layout identical to R3/R4 (~156 MiB, passed).
// ---------------------------------------------------------------------------
extern "C" void kernel_launch(void* const* d_in, const int* in_sizes, int n_in,
                              void* d_out, int out_size, void* d_ws,
                              size_t ws_size, hipStream_t stream) {
  (void)in_sizes; (void)n_in; (void)out_size; (void)ws_size;
  const float* x = (const float*)d_in[0];
  const float* Wqkv = (const float*)d_in[1];
  const float* Wout = (const float*)d_in[2];
  const float* Gq_raw = (const float*)d_in[3];
  const float* llq = (const float*)d_in[4];
  const float* Gk_raw = (const float*)d_in[5];
  const float* llk = (const float*)d_in[6];
  float* out = (float*)d_out;

  const size_t SZ = (size_t)B_DIM * T_DIM * D_DIM;  // 8,388,608
  float* ws = (float*)d_ws;
  float* uq = ws;                 // SZ fp32
  float* vst = ws + SZ;           // SZ fp32 (scores space)
  u16* bstart = (u16*)(ws + 2 * SZ);
  u16* xbf = bstart;              // SZ bf16 (later vT)
  u16* vbf = bstart + SZ;         // SZ
  u16* bq0 = bstart + 2 * SZ;     // SZ (attn alias space)
  u16* bq1 = bstart + 3 * SZ;     // SZ  (final aq; later o1)
  u16* bkf = bstart + 4 * SZ;     // SZ  (final ak)
  u16* wqkvb = bstart + 5 * SZ;                  // 3M
  u16* woutb = wqkvb + 3 * 1024 * 1024;          // 1M
  u16* gqb = woutb + 1024 * 1024;                // 1M
  u16* gkb = gqb + 1024 * 1024;                  // 1M
  (void)bq0; (void)vst;
  // aliases
  float* uk = out;                // d_out hosts u_k until the final GEMM
  float* sc = uq;                 // 2*SZ fp32 over uq+vst
  u16* vT = xbf;                  // after qkv, xbf is dead
  u16* attn = vbf;                // 2*SZ bf16 over vbf+bq0
  u16* o1 = bq1;                  // after scores, aq is dead

  const dim3 blk(256);

  cvt_bf16_kernel<<<dim3((int)(SZ / 4 / 256)), blk, 0, stream>>>(x, xbf,
                                                                 (int)(SZ / 4));
  cvt_bf16_kernel<<<dim3(3 * 1024), blk, 0, stream>>>(Wqkv, wqkvb,
                                                      3 * 1024 * 1024 / 4);
  cvt_bf16_kernel<<<dim3(1024), blk, 0, stream>>>(Wout, woutb,
                                                  1024 * 1024 / 4);
  prep_G_bf16_kernel<<<dim3(4096), blk, 0, stream>>>(Gq_raw, gqb);
  prep_G_bf16_kernel<<<dim3(4096), blk, 0, stream>>>(Gk_raw, gkb);

  // qkv: 1536 blocks, supertile-swizzled
  qkv_mfma_kernel<<<dim3(1536), blk, 0, stream>>>(xbf, wqkvb, uq, uk, vbf);
  // vT (xbf dead now)
  transpose_bf16_kernel<<<dim3(16, 32, 4), blk, 0, stream>>>(vbf, vT);

  // fused LCA v2: both chains, one dispatch, 512-thread blocks
  lca_fused_kernel<<<dim3(512), dim3(512), 0, stream>>>(uq, uk, gqb, gkb, llq,
                                                        llk, bq1, bkf);

  scores_mfma_kernel<<<dim3(16, 16, 4), blk, 0, stream>>>(bq1, bkf, sc);
  softmax_attn_kernel<<<dim3(B_DIM * T_DIM), blk, 0, stream>>>(sc, attn);
  attnv_mfma_kernel<<<dim3(8, 16, 4), blk, 0, stream>>>(attn, vT, o1);
  out_mfma_kernel<<<dim3(8, 64), blk, 0, stream>>>(o1, woutb, out);
}

// Round 6
// 3096.855 us; speedup vs baseline: 1.1581x; 1.1581x over previous
//
#include <hip/hip_runtime.h>
#include <math.h>

#define B_DIM 4
#define T_DIM 2048
#define D_DIM 1024
#define ETA 0.1f
#define N_ITERS 10

typedef unsigned short u16;
typedef __attribute__((ext_vector_type(8))) short bf8_t;   // 8 bf16 (4 VGPRs)
typedef __attribute__((ext_vector_type(4))) float f4_t;    // 4 fp32 acc

__device__ __forceinline__ u16 f2bf(float f) {
  union { float f; unsigned u; } x;
  x.f = f;
  unsigned r = x.u + 0x7FFFu + ((x.u >> 16) & 1u);  // RNE
  return (u16)(r >> 16);
}
__device__ __forceinline__ float bf2f(u16 h) {
  union { unsigned u; float f; } x;
  x.u = ((unsigned)h) << 16;
  return x.f;
}

__device__ __forceinline__ float soft_thresh(float v, float lam) {
  return copysignf(fmaxf(fabsf(v) - lam, 0.0f), v);
}

// ---------------------------------------------------------------------------
// bf16 MFMA NT GEMM core: C(128x128 at m0,n0) = A[M x K] * B^T (B is [N][K]).
// 256 threads = 4 waves (2x2), each wave 64x64 = 4x4 mfma 16x16x32 tiles.
// ---------------------------------------------------------------------------
__device__ __forceinline__ void mfma_gemm_nt(const u16* __restrict__ A,
                                             const u16* __restrict__ Bm,
                                             int lda, int ldb,
                                             int m0, int n0, int kEnd,
                                             f4_t acc[4][4]) {
  __shared__ short As[128][72];
  __shared__ short Bs[128][72];
  const int tid = threadIdx.x;
  const int lane = tid & 63;
  const int wave = tid >> 6;
  const int m16 = lane & 15;
  const int q = lane >> 4;
  const int wrow = (wave >> 1) * 64;
  const int wcol = (wave & 1) * 64;
  const int sr = tid >> 3;   // staging row base (0..31)
  const int sc8 = tid & 7;   // k-octet (8 bf16 = 16B)

  float4 apf[4], bpf[4];
#pragma unroll
  for (int p = 0; p < 4; ++p) {
    apf[p] = *(const float4*)(A + (size_t)(m0 + sr + p * 32) * lda + sc8 * 8);
    bpf[p] = *(const float4*)(Bm + (size_t)(n0 + sr + p * 32) * ldb + sc8 * 8);
  }

  for (int k0 = 0; k0 < kEnd; k0 += 64) {
    __syncthreads();
#pragma unroll
    for (int p = 0; p < 4; ++p) {
      *(float4*)&As[sr + p * 32][sc8 * 8] = apf[p];
      *(float4*)&Bs[sr + p * 32][sc8 * 8] = bpf[p];
    }
    __syncthreads();
    if (k0 + 64 < kEnd) {
      const int kn = k0 + 64 + sc8 * 8;
#pragma unroll
      for (int p = 0; p < 4; ++p) {
        apf[p] = *(const float4*)(A + (size_t)(m0 + sr + p * 32) * lda + kn);
        bpf[p] = *(const float4*)(Bm + (size_t)(n0 + sr + p * 32) * ldb + kn);
      }
    }
#pragma unroll
    for (int s = 0; s < 2; ++s) {
      bf8_t af[4], bb[4];
#pragma unroll
      for (int i = 0; i < 4; ++i)
        af[i] = *(const bf8_t*)&As[wrow + i * 16 + m16][s * 32 + q * 8];
#pragma unroll
      for (int j = 0; j < 4; ++j)
        bb[j] = *(const bf8_t*)&Bs[wcol + j * 16 + m16][s * 32 + q * 8];
#pragma unroll
      for (int i = 0; i < 4; ++i)
#pragma unroll
        for (int j = 0; j < 4; ++j)
          acc[i][j] = __builtin_amdgcn_mfma_f32_16x16x32_bf16(
              af[i], bb[j], acc[i][j], 0, 0, 0);
    }
    __syncthreads();
  }
}

// C/D layout (verified m89): col = lane&15, row = (lane>>4)*4 + reg.
#define EPI_PREAMBLE                                   \
  const int tid = threadIdx.x;                         \
  const int lane = tid & 63;                           \
  const int wave = tid >> 6;                           \
  const int m16 = lane & 15;                           \
  const int q = lane >> 4;                             \
  const int wrow = (wave >> 1) * 64;                   \
  const int wcol = (wave & 1) * 64;

// ---------------------------------------------------------------------------
__global__ __launch_bounds__(256) void cvt_bf16_kernel(
    const float* __restrict__ src, u16* __restrict__ dst, int n4) {
  const int i = blockIdx.x * 256 + threadIdx.x;
  if (i >= n4) return;
  const float4 v = ((const float4*)src)[i];
  ushort4 o;
  o.x = f2bf(v.x); o.y = f2bf(v.y); o.z = f2bf(v.z); o.w = f2bf(v.w);
  ((ushort4*)dst)[i] = o;
}

// ---------------------------------------------------------------------------
__global__ __launch_bounds__(256) void prep_G_bf16_kernel(
    const float* __restrict__ Graw, u16* __restrict__ G) {
  const int idx = blockIdx.x * 256 + threadIdx.x;
  const int i = idx >> 10;
  const int j = idx & 1023;
  const float g =
      (i == j) ? 0.0f : 0.5f * (Graw[idx] + Graw[(size_t)j * D_DIM + i]);
  G[idx] = f2bf(g);
}

// ---------------------------------------------------------------------------
// qkv = x @ Wqkv^T. 1-D grid of 1536 blocks, supertile-swizzled.
// ---------------------------------------------------------------------------
__global__ __launch_bounds__(256) void qkv_mfma_kernel(
    const u16* __restrict__ xbf, const u16* __restrict__ Wbf,
    float* __restrict__ uq, float* __restrict__ uk, u16* __restrict__ vbf) {
  const int bid = blockIdx.x;
  const int g = bid / 192;
  const int r = bid % 192;
  const int m0 = (g * 8 + (r & 7)) * 128;
  const int n0 = (r >> 3) * 128;
  f4_t acc[4][4];
#pragma unroll
  for (int i = 0; i < 4; ++i)
#pragma unroll
    for (int j = 0; j < 4; ++j) acc[i][j] = (f4_t){0.f, 0.f, 0.f, 0.f};
  mfma_gemm_nt(xbf, Wbf, D_DIM, D_DIM, m0, n0, D_DIM, acc);
  EPI_PREAMBLE
  const int which = n0 >> 10;
  const int nloc0 = n0 & 1023;
#pragma unroll
  for (int i = 0; i < 4; ++i)
#pragma unroll
    for (int j = 0; j < 4; ++j) {
      const int cc = nloc0 + wcol + j * 16 + m16;
#pragma unroll
      for (int r2 = 0; r2 < 4; ++r2) {
        const size_t rr = m0 + wrow + i * 16 + q * 4 + r2;
        const float val = acc[i][j][r2];
        if (which == 0)       uq[rr * D_DIM + cc] = val;
        else if (which == 1)  uk[rr * D_DIM + cc] = val;
        else                  vbf[rr * D_DIM + cc] = f2bf(val);
      }
    }
}

// ---------------------------------------------------------------------------
__global__ __launch_bounds__(256) void transpose_bf16_kernel(
    const u16* __restrict__ src, u16* __restrict__ dst) {
  __shared__ short Ls[64][72];
  const int b = blockIdx.z;
  const int d0 = blockIdx.x * 64;
  const int t0 = blockIdx.y * 64;
  const int tid = threadIdx.x;
#pragma unroll
  for (int rep = 0; rep < 2; ++rep) {
    const int u = rep * 256 + tid;
    const int r = u >> 3;
    const int c8 = u & 7;
    const float4 v = *(const float4*)(src + (size_t)b * T_DIM * D_DIM +
                                      (size_t)(t0 + r) * D_DIM + d0 + c8 * 8);
    *(float4*)&Ls[r][c8 * 8] = v;
  }
  __syncthreads();
#pragma unroll
  for (int rep = 0; rep < 2; ++rep) {
    const int u = rep * 256 + tid;
    const int d = u >> 3;
    const int t8 = u & 7;
    union { u16 s[8]; float4 v; } tmp;
#pragma unroll
    for (int l = 0; l < 8; ++l) tmp.s[l] = (u16)Ls[t8 * 8 + l][d];
    *(float4*)(dst + (size_t)b * D_DIM * T_DIM + (size_t)(d0 + d) * T_DIM +
               t0 + t8 * 8) = tmp.v;
  }
}

// ---------------------------------------------------------------------------
// Fused LCA chain v3: all 10 iterations in one kernel.
// 512 threads = 8 waves; block owns 32 rows; wave owns 128 cols.
// Register budget (the R5 spill fix): v fp32 in regs (64), u in LDS bf16
// (not regs), acc 64 AGPR, G-prefetch dbuf 64 VGPR -> ~160 VGPR + 64 AGPR,
// fits 2 waves/SIMD without any launch-bounds cap. NO min-waves arg:
// __launch_bounds__(512) alone caps regs at 256 (8 waves must co-reside).
// LDS: a (66 KB) + u (66 KB) = 132 KB -> 1 block/CU.
// ---------------------------------------------------------------------------
__global__ __launch_bounds__(512) void lca_fused_kernel(
    const float* __restrict__ uqg, const float* __restrict__ ukg,
    const u16* __restrict__ Gq, const u16* __restrict__ Gk,
    const float* __restrict__ llq, const float* __restrict__ llk,
    u16* __restrict__ aq_out, u16* __restrict__ ak_out) {
  __shared__ u16 a_lds[32][1032];  // +8 pad: conflict-free b128 frag reads
  __shared__ u16 u_lds[32][1032];
  const int b = blockIdx.x;
  const int chain = (b >> 2) & 1;                 // b%8: 0-3 q, 4-7 k (XCD map)
  const int mb = ((b >> 3) << 2) | (b & 3);       // 0..255
  const int m0 = mb * 32;
  const float* __restrict__ u = chain ? ukg : uqg;
  const u16* __restrict__ G = chain ? Gk : Gq;
  u16* __restrict__ aout = chain ? ak_out : aq_out;
  const float lam = expf(chain ? llk[0] : llq[0]);

  const int tid = threadIdx.x;
  const int lane = tid & 63;
  const int wave = tid >> 6;      // 0..7
  const int m16 = lane & 15;
  const int q = lane >> 4;
  const int col0 = wave * 128;    // wave's n-slice

  float vreg[2][8][4];

  // ---- init: load u -> LDS(bf16), v = ETA*u, a0 = soft(v)
#pragma unroll
  for (int rt = 0; rt < 2; ++rt)
#pragma unroll
    for (int c8 = 0; c8 < 8; ++c8) {
      const int row = rt * 16 + q * 4;
      const int col = col0 + c8 * 16 + m16;
#pragma unroll
      for (int r = 0; r < 4; ++r) {
        const float uv = u[(size_t)(m0 + row + r) * D_DIM + col];
        u_lds[row + r][col] = f2bf(uv);
        const float v = ETA * uv;
        vreg[rt][c8][r] = v;
        a_lds[row + r][col] = f2bf(soft_thresh(v, lam));
      }
    }

  const u16* gbase = G + (size_t)(col0 + m16) * D_DIM + q * 8;

  for (int it = 1; it < N_ITERS; ++it) {
    __syncthreads();  // a_lds for this iteration fully written
    f4_t acc[2][8];
#pragma unroll
    for (int rt = 0; rt < 2; ++rt)
#pragma unroll
      for (int ct = 0; ct < 8; ++ct) acc[rt][ct] = (f4_t){0.f, 0.f, 0.f, 0.f};

    bf8_t bb0[8], bb1[8];
#pragma unroll
    for (int ct = 0; ct < 8; ++ct)
      bb0[ct] = *(const bf8_t*)(gbase + (size_t)ct * 16 * D_DIM);

    // K-loop unrolled by 64 (2 mfma-K steps): static dbuf indices
    for (int k0 = 0; k0 < D_DIM; k0 += 64) {
      // prefetch k0+32 into bb1
#pragma unroll
      for (int ct = 0; ct < 8; ++ct)
        bb1[ct] = *(const bf8_t*)(gbase + (size_t)ct * 16 * D_DIM + k0 + 32);
      {
        const bf8_t af0 = *(const bf8_t*)&a_lds[m16][k0 + q * 8];
        const bf8_t af1 = *(const bf8_t*)&a_lds[16 + m16][k0 + q * 8];
#pragma unroll
        for (int ct = 0; ct < 8; ++ct) {
          acc[0][ct] = __builtin_amdgcn_mfma_f32_16x16x32_bf16(
              af0, bb0[ct], acc[0][ct], 0, 0, 0);
          acc[1][ct] = __builtin_amdgcn_mfma_f32_16x16x32_bf16(
              af1, bb0[ct], acc[1][ct], 0, 0, 0);
        }
      }
      if (k0 + 64 < D_DIM) {
#pragma unroll
        for (int ct = 0; ct < 8; ++ct)
          bb0[ct] =
              *(const bf8_t*)(gbase + (size_t)ct * 16 * D_DIM + k0 + 64);
      }
      {
        const bf8_t af0 = *(const bf8_t*)&a_lds[m16][k0 + 32 + q * 8];
        const bf8_t af1 = *(const bf8_t*)&a_lds[16 + m16][k0 + 32 + q * 8];
#pragma unroll
        for (int ct = 0; ct < 8; ++ct) {
          acc[0][ct] = __builtin_amdgcn_mfma_f32_16x16x32_bf16(
              af0, bb1[ct], acc[0][ct], 0, 0, 0);
          acc[1][ct] = __builtin_amdgcn_mfma_f32_16x16x32_bf16(
              af1, bb1[ct], acc[1][ct], 0, 0, 0);
        }
      }
    }
    __syncthreads();  // all waves done READING a_lds; safe to overwrite
    const bool last = (it == N_ITERS - 1);
#pragma unroll
    for (int rt = 0; rt < 2; ++rt)
#pragma unroll
      for (int c8 = 0; c8 < 8; ++c8) {
        const int row = rt * 16 + q * 4;
        const int col = col0 + c8 * 16 + m16;
#pragma unroll
        for (int r = 0; r < 4; ++r) {
          const float uu = bf2f(u_lds[row + r][col]);
          float v = vreg[rt][c8][r];
          v += ETA * (uu - v - acc[rt][c8][r]);
          vreg[rt][c8][r] = v;
          const u16 av = f2bf(soft_thresh(v, lam));
          a_lds[row + r][col] = av;
          if (last) aout[(size_t)(m0 + row + r) * D_DIM + col] = av;
        }
      }
  }
}

// ---------------------------------------------------------------------------
__global__ __launch_bounds__(256) void scores_mfma_kernel(
    const u16* __restrict__ aq, const u16* __restrict__ ak,
    float* __restrict__ sc) {
  const int b = blockIdx.z;
  const int m0 = blockIdx.y * 128;
  const int n0 = blockIdx.x * 128;
  if (n0 > m0 + 127) return;  // uniform early exit, before any barrier
  f4_t acc[4][4];
#pragma unroll
  for (int i = 0; i < 4; ++i)
#pragma unroll
    for (int j = 0; j < 4; ++j) acc[i][j] = (f4_t){0.f, 0.f, 0.f, 0.f};
  mfma_gemm_nt(aq + (size_t)b * T_DIM * D_DIM,
               ak + (size_t)b * T_DIM * D_DIM, D_DIM, D_DIM, m0, n0, D_DIM,
               acc);
  EPI_PREAMBLE
  float* out = sc + (size_t)b * T_DIM * T_DIM;
  const float scale = 0.03125f;  // 1/sqrt(1024)
#pragma unroll
  for (int i = 0; i < 4; ++i)
#pragma unroll
    for (int j = 0; j < 4; ++j) {
      const int cc = n0 + wcol + j * 16 + m16;
#pragma unroll
      for (int r = 0; r < 4; ++r) {
        const size_t rr = m0 + wrow + i * 16 + q * 4 + r;
        out[rr * T_DIM + cc] = acc[i][j][r] * scale;
      }
    }
}

// ---------------------------------------------------------------------------
__global__ __launch_bounds__(256) void softmax_attn_kernel(
    const float* __restrict__ sc, u16* __restrict__ attn) {
  const int b = blockIdx.x >> 11;
  const int i = blockIdx.x & (T_DIM - 1);
  const float* row = sc + ((size_t)b * T_DIM + i) * T_DIM;
  u16* arow = attn + ((size_t)b * T_DIM + i) * T_DIM;
  const int len = i + 1;
  const int tid = threadIdx.x;
  __shared__ float red[256];

  float mx = -INFINITY;
  for (int j = tid; j < len; j += 256) mx = fmaxf(mx, row[j]);
  red[tid] = mx;
  __syncthreads();
  for (int s = 128; s > 0; s >>= 1) {
    if (tid < s) red[tid] = fmaxf(red[tid], red[tid + s]);
    __syncthreads();
  }
  mx = red[0];
  __syncthreads();

  float sum = 0.0f;
  for (int j = tid; j < len; j += 256) sum += __expf(row[j] - mx);
  red[tid] = sum;
  __syncthreads();
  for (int s = 128; s > 0; s >>= 1) {
    if (tid < s) red[tid] += red[tid + s];
    __syncthreads();
  }
  const float inv = 1.0f / red[0];

  for (int j = tid; j < len; j += 256)
    arow[j] = f2bf(__expf(row[j] - mx) * inv);
  for (int j = len + tid; j < T_DIM; j += 256) arow[j] = 0;
}

// ---------------------------------------------------------------------------
__global__ __launch_bounds__(256) void attnv_mfma_kernel(
    const u16* __restrict__ attn, const u16* __restrict__ vT,
    u16* __restrict__ o1) {
  const int b = blockIdx.z;
  const int m0 = blockIdx.y * 128;
  const int n0 = blockIdx.x * 128;
  f4_t acc[4][4];
#pragma unroll
  for (int i = 0; i < 4; ++i)
#pragma unroll
    for (int j = 0; j < 4; ++j) acc[i][j] = (f4_t){0.f, 0.f, 0.f, 0.f};
  mfma_gemm_nt(attn + (size_t)b * T_DIM * T_DIM,
               vT + (size_t)b * D_DIM * T_DIM, T_DIM, T_DIM, m0, n0,
               m0 + 128, acc);
  EPI_PREAMBLE
  u16* out = o1 + (size_t)b * T_DIM * D_DIM;
#pragma unroll
  for (int i = 0; i < 4; ++i)
#pragma unroll
    for (int j = 0; j < 4; ++j) {
      const int cc = n0 + wcol + j * 16 + m16;
#pragma unroll
      for (int r = 0; r < 4; ++r) {
        const size_t rr = m0 + wrow + i * 16 + q * 4 + r;
        out[rr * D_DIM + cc] = f2bf(acc[i][j][r]);
      }
    }
}

// ---------------------------------------------------------------------------
__global__ __launch_bounds__(256) void out_mfma_kernel(
    const u16* __restrict__ o1, const u16* __restrict__ Wbf,
    float* __restrict__ out) {
  f4_t acc[4][4];
#pragma unroll
  for (int i = 0; i < 4; ++i)
#pragma unroll
    for (int j = 0; j < 4; ++j) acc[i][j] = (f4_t){0.f, 0.f, 0.f, 0.f};
  const int m0 = blockIdx.y * 128;
  const int n0 = blockIdx.x * 128;
  mfma_gemm_nt(o1, Wbf, D_DIM, D_DIM, m0, n0, D_DIM, acc);
  EPI_PREAMBLE
#pragma unroll
  for (int i = 0; i < 4; ++i)
#pragma unroll
    for (int j = 0; j < 4; ++j) {
      const int cc = n0 + wcol + j * 16 + m16;
#pragma unroll
      for (int r = 0; r < 4; ++r) {
        const size_t rr = m0 + wrow + i * 16 + q * 4 + r;
        out[rr * D_DIM + cc] = acc[i][j][r];
      }
    }
}

// ---------------------------------------------------------------------------
// Workspace layout identical to R3/R4/R5 (~156 MiB, passed).
// ---------------------------------------------------------------------------
extern "C" void kernel_launch(void* const* d_in, const int* in_sizes, int n_in,
                              void* d_out, int out_size, void* d_ws,
                              size_t ws_size, hipStream_t stream) {
  (void)in_sizes; (void)n_in; (void)out_size; (void)ws_size;
  const float* x = (const float*)d_in[0];
  const float* Wqkv = (const float*)d_in[1];
  const float* Wout = (const float*)d_in[2];
  const float* Gq_raw = (const float*)d_in[3];
  const float* llq = (const float*)d_in[4];
  const float* Gk_raw = (const float*)d_in[5];
  const float* llk = (const float*)d_in[6];
  float* out = (float*)d_out;

  const size_t SZ = (size_t)B_DIM * T_DIM * D_DIM;  // 8,388,608
  float* ws = (float*)d_ws;
  float* uq = ws;                 // SZ fp32
  float* vst = ws + SZ;           // SZ fp32 (scores space)
  u16* bstart = (u16*)(ws + 2 * SZ);
  u16* xbf = bstart;              // SZ bf16 (later vT)
  u16* vbf = bstart + SZ;         // SZ
  u16* bq0 = bstart + 2 * SZ;     // SZ (attn alias space)
  u16* bq1 = bstart + 3 * SZ;     // SZ  (final aq; later o1)
  u16* bkf = bstart + 4 * SZ;     // SZ  (final ak)
  u16* wqkvb = bstart + 5 * SZ;                  // 3M
  u16* woutb = wqkvb + 3 * 1024 * 1024;          // 1M
  u16* gqb = woutb + 1024 * 1024;                // 1M
  u16* gkb = gqb + 1024 * 1024;                  // 1M
  (void)bq0; (void)vst;
  // aliases
  float* uk = out;                // d_out hosts u_k until the final GEMM
  float* sc = uq;                 // 2*SZ fp32 over uq+vst
  u16* vT = xbf;                  // after qkv, xbf is dead
  u16* attn = vbf;                // 2*SZ bf16 over vbf+bq0
  u16* o1 = bq1;                  // after scores, aq is dead

  const dim3 blk(256);

  cvt_bf16_kernel<<<dim3((int)(SZ / 4 / 256)), blk, 0, stream>>>(x, xbf,
                                                                 (int)(SZ / 4));
  cvt_bf16_kernel<<<dim3(3 * 1024), blk, 0, stream>>>(Wqkv, wqkvb,
                                                      3 * 1024 * 1024 / 4);
  cvt_bf16_kernel<<<dim3(1024), blk, 0, stream>>>(Wout, woutb,
                                                  1024 * 1024 / 4);
  prep_G_bf16_kernel<<<dim3(4096), blk, 0, stream>>>(Gq_raw, gqb);
  prep_G_bf16_kernel<<<dim3(4096), blk, 0, stream>>>(Gk_raw, gkb);

  // qkv: 1536 blocks, supertile-swizzled
  qkv_mfma_kernel<<<dim3(1536), blk, 0, stream>>>(xbf, wqkvb, uq, uk, vbf);
  // vT (xbf dead now)
  transpose_bf16_kernel<<<dim3(16, 32, 4), blk, 0, stream>>>(vbf, vT);

  // fused LCA v3: both chains, one dispatch, 512-thread blocks
  lca_fused_kernel<<<dim3(512), dim3(512), 0, stream>>>(uq, uk, gqb, gkb, llq,
                                                        llk, bq1, bkf);

  scores_mfma_kernel<<<dim3(16, 16, 4), blk, 0, stream>>>(bq1, bkf, sc);
  softmax_attn_kernel<<<dim3(B_DIM * T_DIM), blk, 0, stream>>>(sc, attn);
  attnv_mfma_kernel<<<dim3(8, 16, 4), blk, 0, stream>>>(attn, vT, o1);
  out_mfma_kernel<<<dim3(8, 64), blk, 0, stream>>>(o1, woutb, out);
}

// Round 7
// 1209.620 us; speedup vs baseline: 2.9650x; 2.5602x over previous
//
#include <hip/hip_runtime.h>
#include <math.h>

#define B_DIM 4
#define T_DIM 2048
#define D_DIM 1024
#define ETA 0.1f
#define N_ITERS 10

typedef unsigned short u16;
typedef __attribute__((ext_vector_type(8))) short bf8_t;   // 8 bf16 (4 VGPRs)
typedef __attribute__((ext_vector_type(4))) float f4_t;    // 4 fp32 acc
typedef __attribute__((ext_vector_type(16))) float f16v;   // 16 fp32 acc (32x32)

__device__ __forceinline__ u16 f2bf(float f) {
  union { float f; unsigned u; } x;
  x.f = f;
  unsigned r = x.u + 0x7FFFu + ((x.u >> 16) & 1u);  // RNE
  return (u16)(r >> 16);
}
__device__ __forceinline__ float bf2f(u16 h) {
  union { unsigned u; float f; } x;
  x.u = ((unsigned)h) << 16;
  return x.f;
}

__device__ __forceinline__ float soft_thresh(float v, float lam) {
  return copysignf(fmaxf(fabsf(v) - lam, 0.0f), v);
}

// ---------------------------------------------------------------------------
// bf16 MFMA NT GEMM core: C(128x128 at m0,n0) = A[M x K] * B^T (B is [N][K]).
// 256 threads = 4 waves (2x2), each wave 64x64 = 4x4 mfma 16x16x32 tiles.
// ---------------------------------------------------------------------------
__device__ __forceinline__ void mfma_gemm_nt(const u16* __restrict__ A,
                                             const u16* __restrict__ Bm,
                                             int lda, int ldb,
                                             int m0, int n0, int kEnd,
                                             f4_t acc[4][4]) {
  __shared__ short As[128][72];
  __shared__ short Bs[128][72];
  const int tid = threadIdx.x;
  const int lane = tid & 63;
  const int wave = tid >> 6;
  const int m16 = lane & 15;
  const int q = lane >> 4;
  const int wrow = (wave >> 1) * 64;
  const int wcol = (wave & 1) * 64;
  const int sr = tid >> 3;   // staging row base (0..31)
  const int sc8 = tid & 7;   // k-octet (8 bf16 = 16B)

  float4 apf[4], bpf[4];
#pragma unroll
  for (int p = 0; p < 4; ++p) {
    apf[p] = *(const float4*)(A + (size_t)(m0 + sr + p * 32) * lda + sc8 * 8);
    bpf[p] = *(const float4*)(Bm + (size_t)(n0 + sr + p * 32) * ldb + sc8 * 8);
  }

  for (int k0 = 0; k0 < kEnd; k0 += 64) {
    __syncthreads();
#pragma unroll
    for (int p = 0; p < 4; ++p) {
      *(float4*)&As[sr + p * 32][sc8 * 8] = apf[p];
      *(float4*)&Bs[sr + p * 32][sc8 * 8] = bpf[p];
    }
    __syncthreads();
    if (k0 + 64 < kEnd) {
      const int kn = k0 + 64 + sc8 * 8;
#pragma unroll
      for (int p = 0; p < 4; ++p) {
        apf[p] = *(const float4*)(A + (size_t)(m0 + sr + p * 32) * lda + kn);
        bpf[p] = *(const float4*)(Bm + (size_t)(n0 + sr + p * 32) * ldb + kn);
      }
    }
#pragma unroll
    for (int s = 0; s < 2; ++s) {
      bf8_t af[4], bb[4];
#pragma unroll
      for (int i = 0; i < 4; ++i)
        af[i] = *(const bf8_t*)&As[wrow + i * 16 + m16][s * 32 + q * 8];
#pragma unroll
      for (int j = 0; j < 4; ++j)
        bb[j] = *(const bf8_t*)&Bs[wcol + j * 16 + m16][s * 32 + q * 8];
#pragma unroll
      for (int i = 0; i < 4; ++i)
#pragma unroll
        for (int j = 0; j < 4; ++j)
          acc[i][j] = __builtin_amdgcn_mfma_f32_16x16x32_bf16(
              af[i], bb[j], acc[i][j], 0, 0, 0);
    }
    __syncthreads();
  }
}

// C/D layout 16x16 (verified m89): col = lane&15, row = (lane>>4)*4 + reg.
#define EPI_PREAMBLE                                   \
  const int tid = threadIdx.x;                         \
  const int lane = tid & 63;                           \
  const int wave = tid >> 6;                           \
  const int m16 = lane & 15;                           \
  const int q = lane >> 4;                             \
  const int wrow = (wave >> 1) * 64;                   \
  const int wcol = (wave & 1) * 64;

// ---------------------------------------------------------------------------
__global__ __launch_bounds__(256) void cvt_bf16_kernel(
    const float* __restrict__ src, u16* __restrict__ dst, int n4) {
  const int i = blockIdx.x * 256 + threadIdx.x;
  if (i >= n4) return;
  const float4 v = ((const float4*)src)[i];
  ushort4 o;
  o.x = f2bf(v.x); o.y = f2bf(v.y); o.z = f2bf(v.z); o.w = f2bf(v.w);
  ((ushort4*)dst)[i] = o;
}

// ---------------------------------------------------------------------------
// G -> fragment-sequential swizzled layout for mfma_32x32x16 B-operand:
// Gsw[t][c][lane][8] with n = t*32 + (lane&31), k = c*16 + (lane>>5)*8 + j.
// Each (wave,tile,k-step) fragment load becomes base + lane*16B: coalesced.
// G = 0.5*(Graw+Graw^T), zero diag, bf16.
// ---------------------------------------------------------------------------
__global__ __launch_bounds__(256) void prep_Gsw_kernel(
    const float* __restrict__ Graw, u16* __restrict__ Gsw) {
  const int idx = blockIdx.x * 256 + threadIdx.x;  // 0 .. 32*64*64-1
  const int lane = idx & 63;
  const int c = (idx >> 6) & 63;
  const int t = idx >> 12;
  const int n = t * 32 + (lane & 31);
  const int k0 = c * 16 + (lane >> 5) * 8;
  union { u16 s[8]; float4 v; } o;
#pragma unroll
  for (int j = 0; j < 8; ++j) {
    const int k = k0 + j;
    const float g = (n == k)
        ? 0.0f
        : 0.5f * (Graw[(size_t)n * D_DIM + k] + Graw[(size_t)k * D_DIM + n]);
    o.s[j] = f2bf(g);
  }
  *(float4*)(Gsw + (size_t)idx * 8) = o.v;
}

// ---------------------------------------------------------------------------
// qkv = x @ Wqkv^T -> all outputs bf16: uqb / ukb (in d_out) / vbf.
// 1-D grid of 1536 blocks, supertile-swizzled for L2 locality.
// ---------------------------------------------------------------------------
__global__ __launch_bounds__(256) void qkv_mfma_kernel(
    const u16* __restrict__ xbf, const u16* __restrict__ Wbf,
    u16* __restrict__ uqb, u16* __restrict__ ukb, u16* __restrict__ vbf) {
  const int bid = blockIdx.x;
  const int g = bid / 192;
  const int r = bid % 192;
  const int m0 = (g * 8 + (r & 7)) * 128;
  const int n0 = (r >> 3) * 128;
  f4_t acc[4][4];
#pragma unroll
  for (int i = 0; i < 4; ++i)
#pragma unroll
    for (int j = 0; j < 4; ++j) acc[i][j] = (f4_t){0.f, 0.f, 0.f, 0.f};
  mfma_gemm_nt(xbf, Wbf, D_DIM, D_DIM, m0, n0, D_DIM, acc);
  EPI_PREAMBLE
  const int which = n0 >> 10;
  u16* dst = (which == 0) ? uqb : ((which == 1) ? ukb : vbf);
  const int nloc0 = n0 & 1023;
#pragma unroll
  for (int i = 0; i < 4; ++i)
#pragma unroll
    for (int j = 0; j < 4; ++j) {
      const int cc = nloc0 + wcol + j * 16 + m16;
#pragma unroll
      for (int r2 = 0; r2 < 4; ++r2) {
        const size_t rr = m0 + wrow + i * 16 + q * 4 + r2;
        dst[rr * D_DIM + cc] = f2bf(acc[i][j][r2]);
      }
    }
}

// ---------------------------------------------------------------------------
__global__ __launch_bounds__(256) void transpose_bf16_kernel(
    const u16* __restrict__ src, u16* __restrict__ dst) {
  __shared__ short Ls[64][72];
  const int b = blockIdx.z;
  const int d0 = blockIdx.x * 64;
  const int t0 = blockIdx.y * 64;
  const int tid = threadIdx.x;
#pragma unroll
  for (int rep = 0; rep < 2; ++rep) {
    const int u = rep * 256 + tid;
    const int r = u >> 3;
    const int c8 = u & 7;
    const float4 v = *(const float4*)(src + (size_t)b * T_DIM * D_DIM +
                                      (size_t)(t0 + r) * D_DIM + d0 + c8 * 8);
    *(float4*)&Ls[r][c8 * 8] = v;
  }
  __syncthreads();
#pragma unroll
  for (int rep = 0; rep < 2; ++rep) {
    const int u = rep * 256 + tid;
    const int d = u >> 3;
    const int t8 = u & 7;
    union { u16 s[8]; float4 v; } tmp;
#pragma unroll
    for (int l = 0; l < 8; ++l) tmp.s[l] = (u16)Ls[t8 * 8 + l][d];
    *(float4*)(dst + (size_t)b * D_DIM * T_DIM + (size_t)(d0 + d) * T_DIM +
               t0 + t8 * 8) = tmp.v;
  }
}

// ---------------------------------------------------------------------------
// Fused LCA chain v4: all 10 iterations in one kernel, mfma_32x32x16.
// 512 threads = 8 waves; block owns 32 rows; wave owns 128 cols (4 n-tiles
// of 32). a in LDS (66 KB only). u re-read from global bf16 (L3-resident).
// G pre-swizzled (Gsw): every fragment load = base + lane*16B, coalesced,
// register-double-buffered. VGPR budget ~124 (+64 AGPR acc): no spill at the
// compiler's 128-arch-VGPR allocation for 512-thread blocks.
// C/D 32x32 layout (verified m74/m101): col=lane&31,
// row=(reg&3)+8*(reg>>2)+4*(lane>>5).
// ---------------------------------------------------------------------------
__global__ __launch_bounds__(512) void lca_fused_kernel(
    const u16* __restrict__ uqb, const u16* __restrict__ ukb,
    const u16* __restrict__ Gqsw, const u16* __restrict__ Gksw,
    const float* __restrict__ llq, const float* __restrict__ llk,
    u16* __restrict__ aq_out, u16* __restrict__ ak_out) {
  __shared__ u16 a_lds[32][1032];
  const int b = blockIdx.x;
  const int chain = (b >> 2) & 1;                 // b%8: 0-3 q, 4-7 k (XCD map)
  const int mb = ((b >> 3) << 2) | (b & 3);       // 0..255
  const int m0 = mb * 32;
  const u16* __restrict__ ub = chain ? ukb : uqb;
  const u16* __restrict__ Gsw = chain ? Gksw : Gqsw;
  u16* __restrict__ aout = chain ? ak_out : aq_out;
  const float lam = expf(chain ? llk[0] : llq[0]);

  const int tid = threadIdx.x;
  const int lane = tid & 63;
  const int wave = tid >> 6;      // 0..7
  const int n32 = lane & 31;
  const int l5 = lane >> 5;       // 0/1
  const int col0 = wave * 128;

  float vreg[4][16];

  // ---- init (iter 0): v = ETA*u ; a0 = soft(v) into a_lds
#pragma unroll
  for (int nt = 0; nt < 4; ++nt) {
    const int col_g = col0 + nt * 32 + n32;
#pragma unroll
    for (int reg = 0; reg < 16; ++reg) {
      const int row = (reg & 3) + 8 * (reg >> 2) + 4 * l5;
      const float uu = bf2f(ub[(size_t)(m0 + row) * D_DIM + col_g]);
      const float v = ETA * uu;
      vreg[nt][reg] = v;
      a_lds[row][col_g] = f2bf(soft_thresh(v, lam));
    }
  }

  // per-tile fragment base: Gsw + t*64*512 + lane*8 (elems); step c = +512
  const u16* gb[4];
#pragma unroll
  for (int nt = 0; nt < 4; ++nt)
    gb[nt] = Gsw + ((size_t)(wave * 4 + nt) * 64) * 512 + lane * 8;

  for (int it = 1; it < N_ITERS; ++it) {
    __syncthreads();  // a_lds complete (init or previous epilogue)
    f16v acc[4];
#pragma unroll
    for (int nt = 0; nt < 4; ++nt)
#pragma unroll
      for (int r = 0; r < 16; ++r) acc[nt][r] = 0.0f;

    bf8_t bb0[4], bb1[4];
#pragma unroll
    for (int nt = 0; nt < 4; ++nt) bb0[nt] = *(const bf8_t*)(gb[nt]);

#pragma unroll 1
    for (int c = 0; c < 64; c += 2) {
#pragma unroll
      for (int nt = 0; nt < 4; ++nt)
        bb1[nt] = *(const bf8_t*)(gb[nt] + (size_t)(c + 1) * 512);
      {
        const bf8_t af = *(const bf8_t*)&a_lds[n32][c * 16 + l5 * 8];
#pragma unroll
        for (int nt = 0; nt < 4; ++nt)
          acc[nt] = __builtin_amdgcn_mfma_f32_32x32x16_bf16(af, bb0[nt],
                                                            acc[nt], 0, 0, 0);
      }
      if (c + 2 < 64) {
#pragma unroll
        for (int nt = 0; nt < 4; ++nt)
          bb0[nt] = *(const bf8_t*)(gb[nt] + (size_t)(c + 2) * 512);
      }
      {
        const bf8_t af = *(const bf8_t*)&a_lds[n32][(c + 1) * 16 + l5 * 8];
#pragma unroll
        for (int nt = 0; nt < 4; ++nt)
          acc[nt] = __builtin_amdgcn_mfma_f32_32x32x16_bf16(af, bb1[nt],
                                                            acc[nt], 0, 0, 0);
      }
    }
    __syncthreads();  // all waves done READING a_lds; safe to overwrite

    const bool last = (it == N_ITERS - 1);
#pragma unroll
    for (int nt = 0; nt < 4; ++nt) {
      const int col_g = col0 + nt * 32 + n32;
#pragma unroll
      for (int reg = 0; reg < 16; ++reg) {
        const int row = (reg & 3) + 8 * (reg >> 2) + 4 * l5;
        const float uu = bf2f(ub[(size_t)(m0 + row) * D_DIM + col_g]);
        float v = vreg[nt][reg];
        v += ETA * (uu - v - acc[nt][reg]);
        vreg[nt][reg] = v;
        const u16 av = f2bf(soft_thresh(v, lam));
        a_lds[row][col_g] = av;
        if (last) aout[(size_t)(m0 + row) * D_DIM + col_g] = av;
      }
    }
  }
}

// ---------------------------------------------------------------------------
__global__ __launch_bounds__(256) void scores_mfma_kernel(
    const u16* __restrict__ aq, const u16* __restrict__ ak,
    float* __restrict__ sc) {
  const int b = blockIdx.z;
  const int m0 = blockIdx.y * 128;
  const int n0 = blockIdx.x * 128;
  if (n0 > m0 + 127) return;  // uniform early exit, before any barrier
  f4_t acc[4][4];
#pragma unroll
  for (int i = 0; i < 4; ++i)
#pragma unroll
    for (int j = 0; j < 4; ++j) acc[i][j] = (f4_t){0.f, 0.f, 0.f, 0.f};
  mfma_gemm_nt(aq + (size_t)b * T_DIM * D_DIM,
               ak + (size_t)b * T_DIM * D_DIM, D_DIM, D_DIM, m0, n0, D_DIM,
               acc);
  EPI_PREAMBLE
  float* out = sc + (size_t)b * T_DIM * T_DIM;
  const float scale = 0.03125f;  // 1/sqrt(1024)
#pragma unroll
  for (int i = 0; i < 4; ++i)
#pragma unroll
    for (int j = 0; j < 4; ++j) {
      const int cc = n0 + wcol + j * 16 + m16;
#pragma unroll
      for (int r = 0; r < 4; ++r) {
        const size_t rr = m0 + wrow + i * 16 + q * 4 + r;
        out[rr * T_DIM + cc] = acc[i][j][r] * scale;
      }
    }
}

// ---------------------------------------------------------------------------
__global__ __launch_bounds__(256) void softmax_attn_kernel(
    const float* __restrict__ sc, u16* __restrict__ attn) {
  const int b = blockIdx.x >> 11;
  const int i = blockIdx.x & (T_DIM - 1);
  const float* row = sc + ((size_t)b * T_DIM + i) * T_DIM;
  u16* arow = attn + ((size_t)b * T_DIM + i) * T_DIM;
  const int len = i + 1;
  const int tid = threadIdx.x;
  __shared__ float red[256];

  float mx = -INFINITY;
  for (int j = tid; j < len; j += 256) mx = fmaxf(mx, row[j]);
  red[tid] = mx;
  __syncthreads();
  for (int s = 128; s > 0; s >>= 1) {
    if (tid < s) red[tid] = fmaxf(red[tid], red[tid + s]);
    __syncthreads();
  }
  mx = red[0];
  __syncthreads();

  float sum = 0.0f;
  for (int j = tid; j < len; j += 256) sum += __expf(row[j] - mx);
  red[tid] = sum;
  __syncthreads();
  for (int s = 128; s > 0; s >>= 1) {
    if (tid < s) red[tid] += red[tid + s];
    __syncthreads();
  }
  const float inv = 1.0f / red[0];

  for (int j = tid; j < len; j += 256)
    arow[j] = f2bf(__expf(row[j] - mx) * inv);
  for (int j = len + tid; j < T_DIM; j += 256) arow[j] = 0;
}

// ---------------------------------------------------------------------------
__global__ __launch_bounds__(256) void attnv_mfma_kernel(
    const u16* __restrict__ attn, const u16* __restrict__ vT,
    u16* __restrict__ o1) {
  const int b = blockIdx.z;
  const int m0 = blockIdx.y * 128;
  const int n0 = blockIdx.x * 128;
  f4_t acc[4][4];
#pragma unroll
  for (int i = 0; i < 4; ++i)
#pragma unroll
    for (int j = 0; j < 4; ++j) acc[i][j] = (f4_t){0.f, 0.f, 0.f, 0.f};
  mfma_gemm_nt(attn + (size_t)b * T_DIM * T_DIM,
               vT + (size_t)b * D_DIM * T_DIM, T_DIM, T_DIM, m0, n0,
               m0 + 128, acc);
  EPI_PREAMBLE
  u16* out = o1 + (size_t)b * T_DIM * D_DIM;
#pragma unroll
  for (int i = 0; i < 4; ++i)
#pragma unroll
    for (int j = 0; j < 4; ++j) {
      const int cc = n0 + wcol + j * 16 + m16;
#pragma unroll
      for (int r = 0; r < 4; ++r) {
        const size_t rr = m0 + wrow + i * 16 + q * 4 + r;
        out[rr * D_DIM + cc] = f2bf(acc[i][j][r]);
      }
    }
}

// ---------------------------------------------------------------------------
__global__ __launch_bounds__(256) void out_mfma_kernel(
    const u16* __restrict__ o1, const u16* __restrict__ Wbf,
    float* __restrict__ out) {
  f4_t acc[4][4];
#pragma unroll
  for (int i = 0; i < 4; ++i)
#pragma unroll
    for (int j = 0; j < 4; ++j) acc[i][j] = (f4_t){0.f, 0.f, 0.f, 0.f};
  const int m0 = blockIdx.y * 128;
  const int n0 = blockIdx.x * 128;
  mfma_gemm_nt(o1, Wbf, D_DIM, D_DIM, m0, n0, D_DIM, acc);
  EPI_PREAMBLE
#pragma unroll
  for (int i = 0; i < 4; ++i)
#pragma unroll
    for (int j = 0; j < 4; ++j) {
      const int cc = n0 + wcol + j * 16 + m16;
#pragma unroll
      for (int r = 0; r < 4; ++r) {
        const size_t rr = m0 + wrow + i * 16 + q * 4 + r;
        out[rr * D_DIM + cc] = acc[i][j][r];
      }
    }
}

// ---------------------------------------------------------------------------
// Workspace (SZ = B*T*D = 8,388,608), total ~156 MiB (same as proven):
//   R0: 2*SZ fp32 (64 MiB) = scores; hosts xbf (bf16 x) early (dead by then)
//   uqb, vbf, vT, bq1(aq), bkf(ak): 5 x SZ u16 (80 MiB)
//   wqkvb 3M, woutb 1M, gqsw 1M, gksw 1M u16 (12 MiB)
// ukb (bf16 u_k) lives in d_out, fully overwritten by the final GEMM.
// attn (2*SZ u16) over [bq1|bkf] (dead after scores); o1 over uqb (dead).
// ---------------------------------------------------------------------------
extern "C" void kernel_launch(void* const* d_in, const int* in_sizes, int n_in,
                              void* d_out, int out_size, void* d_ws,
                              size_t ws_size, hipStream_t stream) {
  (void)in_sizes; (void)n_in; (void)out_size; (void)ws_size;
  const float* x = (const float*)d_in[0];
  const float* Wqkv = (const float*)d_in[1];
  const float* Wout = (const float*)d_in[2];
  const float* Gq_raw = (const float*)d_in[3];
  const float* llq = (const float*)d_in[4];
  const float* Gk_raw = (const float*)d_in[5];
  const float* llk = (const float*)d_in[6];
  float* out = (float*)d_out;

  const size_t SZ = (size_t)B_DIM * T_DIM * D_DIM;  // 8,388,608
  u16* base = (u16*)d_ws;
  float* sc = (float*)base;          // 2*SZ fp32 (= 4*SZ u16)
  u16* xbf = base;                   // bf16 x over R0 start (dead before sc)
  u16* uqb = base + 4 * SZ;
  u16* vbf = base + 5 * SZ;
  u16* vT  = base + 6 * SZ;
  u16* bq1 = base + 7 * SZ;          // final aq
  u16* bkf = base + 8 * SZ;          // final ak
  u16* wqkvb = base + 9 * SZ;                    // 3M
  u16* woutb = wqkvb + 3 * 1024 * 1024;          // 1M
  u16* gqsw = woutb + 1024 * 1024;               // 1M
  u16* gksw = gqsw + 1024 * 1024;                // 1M
  u16* ukb = (u16*)d_out;            // bf16 u_k in d_out until final GEMM
  u16* attn = bq1;                   // 2*SZ over bq1+bkf (dead after scores)
  u16* o1 = uqb;                     // dead after LCA

  const dim3 blk(256);

  cvt_bf16_kernel<<<dim3((int)(SZ / 4 / 256)), blk, 0, stream>>>(x, xbf,
                                                                 (int)(SZ / 4));
  cvt_bf16_kernel<<<dim3(3 * 1024), blk, 0, stream>>>(Wqkv, wqkvb,
                                                      3 * 1024 * 1024 / 4);
  cvt_bf16_kernel<<<dim3(1024), blk, 0, stream>>>(Wout, woutb,
                                                  1024 * 1024 / 4);
  prep_Gsw_kernel<<<dim3(512), blk, 0, stream>>>(Gq_raw, gqsw);
  prep_Gsw_kernel<<<dim3(512), blk, 0, stream>>>(Gk_raw, gksw);

  // qkv: 1536 blocks, supertile-swizzled; bf16 outputs
  qkv_mfma_kernel<<<dim3(1536), blk, 0, stream>>>(xbf, wqkvb, uqb, ukb, vbf);
  transpose_bf16_kernel<<<dim3(16, 32, 4), blk, 0, stream>>>(vbf, vT);

  // fused LCA v4: both chains, one dispatch, 512-thread blocks
  lca_fused_kernel<<<dim3(512), dim3(512), 0, stream>>>(uqb, ukb, gqsw, gksw,
                                                        llq, llk, bq1, bkf);

  scores_mfma_kernel<<<dim3(16, 16, 4), blk, 0, stream>>>(bq1, bkf, sc);
  softmax_attn_kernel<<<dim3(B_DIM * T_DIM), blk, 0, stream>>>(sc, attn);
  attnv_mfma_kernel<<<dim3(8, 16, 4), blk, 0, stream>>>(attn, vT, o1);
  out_mfma_kernel<<<dim3(8, 64), blk, 0, stream>>>(o1, woutb, out);
}